// Round 7
// baseline (276.694 us; speedup 1.0000x reference)
//
#include <hip/hip_runtime.h>
#include <math.h>

#define BB 2
#define TT 2048
#define DD 2048
#define EE 8
#define CCv 512
#define OO1 256

typedef unsigned short u16;
typedef __bf16 bf16x8 __attribute__((ext_vector_type(8)));
typedef float f32x4 __attribute__((ext_vector_type(4)));

__device__ __forceinline__ u16 f2bf(float f) {
    unsigned u = __float_as_uint(f);
    unsigned r = (u + 0x7fffu + ((u >> 16) & 1u)) >> 16;
    return (u16)r;
}

__device__ __forceinline__ void gload16(const void* g, void* s) {
    __builtin_amdgcn_global_load_lds(
        (const __attribute__((address_space(1))) void*)g,
        (__attribute__((address_space(3))) void*)s, 16, 0, 0);
}

// ---------------- fp32 -> bf16 straight convert (vectorized) ----------------
__global__ __launch_bounds__(256) void conv_cast(const float* __restrict__ in,
                                                 u16* __restrict__ out, long n) {
    long i = ((long)blockIdx.x * 256 + threadIdx.x) * 4;
    float4 v = *(const float4*)&in[i];
    ushort4 o; o.x = f2bf(v.x); o.y = f2bf(v.y); o.z = f2bf(v.z); o.w = f2bf(v.w);
    *(ushort4*)&out[i] = o;
}

// ---------------- out[i] += part[i] (fp32, vectorized) ----------------
__global__ __launch_bounds__(256) void add_inplace(float* __restrict__ out,
                                                   const float* __restrict__ part) {
    long i = ((long)blockIdx.x * 256 + threadIdx.x) * 4;
    float4 a = *(float4*)&out[i];
    float4 b = *(const float4*)&part[i];
    a.x += b.x; a.y += b.y; a.z += b.z; a.w += b.w;
    *(float4*)&out[i] = a;
}

// ---------------- tiled transpose + convert: out[z][c][t] = in[z][t][c] ----------------
__global__ __launch_bounds__(256) void transpose_conv(
    const float* __restrict__ in, long inHi, long inLo, int modZ, long sIn,
    u16* __restrict__ out, long outZ, long sOut)
{
    __shared__ float tile[32][33];
    const int z = blockIdx.z;
    const float* ib = in + (long)(z / modZ) * inHi + (long)(z % modZ) * inLo;
    u16* ob = out + (long)z * outZ;
    const int t0 = blockIdx.y * 32, c0 = blockIdx.x * 32;
    const int tid = threadIdx.x;
    const int r = tid >> 3, c4 = (tid & 7) * 4;

    float4 v = *(const float4*)&ib[(long)(t0 + r) * sIn + c0 + c4];
    tile[r][c4 + 0] = v.x; tile[r][c4 + 1] = v.y;
    tile[r][c4 + 2] = v.z; tile[r][c4 + 3] = v.w;
    __syncthreads();

    const int oc = tid >> 3, t4 = (tid & 7) * 4;
    ushort4 o;
    o.x = f2bf(tile[t4 + 0][oc]);
    o.y = f2bf(tile[t4 + 1][oc]);
    o.z = f2bf(tile[t4 + 2][oc]);
    o.w = f2bf(tile[t4 + 3][oc]);
    *(ushort4*)&ob[(long)(c0 + oc) * sOut + t0 + t4] = o;
}

// ---------------- small 128x128 m97-structure GEMM (GEMM2 / GEMM3) ----------------
template<int EPI>
__global__ __launch_bounds__(256)
void mfma_gemm(const u16* __restrict__ A, long ldA, long aHi, long aLo, int modA,
               const u16* __restrict__ B, long ldB, long bHi, long bLo, int modB,
               void* __restrict__ Cout, long ldC, long cHi, long cLo, int modC,
               const float* __restrict__ bias, long biasLo, int modBias,
               int M, int N, int K)
{
    __shared__ __align__(16) char smem[32768];
    char* smA = smem;
    char* smB = smem + 16384;

    const int z = blockIdx.z;
    const char* Ab = (const char*)(A + (long)(z / modA) * aHi + (long)(z % modA) * aLo);
    const char* Bb = (const char*)(B + (long)(z / modB) * bHi + (long)(z % modB) * bLo);
    const long ldAb = ldA * 2, ldBb = ldB * 2;

    const int m0 = blockIdx.y * 128, n0 = blockIdx.x * 128;
    const int tid = threadIdx.x;
    const int l = tid & 63;
    const int w = tid >> 6;
    const int wm = w >> 1, wn = w & 1;

    const int srow = l >> 3;
    const int schunk = (l & 7) ^ srow;
    const int frow = l & 15;
    const int fgrp = l >> 4;
    const int fch0 = fgrp ^ (l & 7);

    int aoff[4], boff[4];
#pragma unroll
    for (int i = 0; i < 4; ++i) {
        aoff[i] = (wm * 64 + i * 16 + frow) * 128 + fch0 * 16;
        boff[i] = (wn * 64 + i * 16 + frow) * 128 + fch0 * 16;
    }

    f32x4 acc[4][4];
    const f32x4 zero4 = {0.f, 0.f, 0.f, 0.f};
#pragma unroll
    for (int i = 0; i < 4; ++i)
#pragma unroll
        for (int j = 0; j < 4; ++j) acc[i][j] = zero4;

    const long sgo = (long)schunk * 16;

    for (int k0 = 0; k0 < K; k0 += 64) {
        const long kb = (long)k0 * 2;
#pragma unroll
        for (int j = 0; j < 4; ++j) {
            const int rr = (j * 4 + w) * 8 + srow;
            gload16(Ab + (long)(m0 + rr) * ldAb + kb + sgo, smA + (j * 4 + w) * 1024);
            gload16(Bb + (long)(n0 + rr) * ldBb + kb + sgo, smB + (j * 4 + w) * 1024);
        }
        __syncthreads();
#pragma unroll
        for (int kk = 0; kk < 2; ++kk) {
            const int kx = kk * 64;
            bf16x8 af[4], bfr[4];
#pragma unroll
            for (int i = 0; i < 4; ++i) af[i] = *(const bf16x8*)(smA + (aoff[i] ^ kx));
#pragma unroll
            for (int i = 0; i < 4; ++i) bfr[i] = *(const bf16x8*)(smB + (boff[i] ^ kx));
#pragma unroll
            for (int mi = 0; mi < 4; ++mi)
#pragma unroll
                for (int ni = 0; ni < 4; ++ni)
                    acc[mi][ni] = __builtin_amdgcn_mfma_f32_16x16x32_bf16(
                        af[mi], bfr[ni], acc[mi][ni], 0, 0, 0);
        }
        __syncthreads();
    }

    const long cbase = (long)(z / modC) * cHi + (long)(z % modC) * cLo;
    const float* biasB = bias + (long)(z % modBias) * biasLo;
#pragma unroll
    for (int mi = 0; mi < 4; ++mi) {
#pragma unroll
        for (int ni = 0; ni < 4; ++ni) {
            const int col = n0 + wn * 64 + ni * 16 + frow;
            const int rowb = m0 + wm * 64 + mi * 16 + fgrp * 4;
#pragma unroll
            for (int r = 0; r < 4; ++r) {
                float v = acc[mi][ni][r];
                const int row = rowb + r;
                if (EPI == 1) {
                    v += biasB[col];
                    v = 0.5f * v * (1.0f + erff(v * 0.70710678118654752f));
                } else {
                    v += biasB[row];
                }
                ((u16*)Cout)[cbase + (long)row * ldC + col] = f2bf(v);
            }
        }
    }
}

// ---------------- 256x256 deep-slack pipelined GEMM (GEMM1 / GEMM4-splitK) ----------
// 8 waves (2M x 4N), wave tile 128x64. LDS: 2 buffers x 64KB (A0|A1|B0|B1 halves).
// Per K-tile: ONE vmcnt(0) + ONE barrier at tile top (only burst(kt) outstanding ->
// precise wait, issued a full tile (~4 phases) earlier), then burst-issue all 8
// gloads of tile kt+1 into the idle buffer, then 4 dataflow phases of 16 MFMAs
// (Q00,Q01,Q11,Q10 gray order) each pinned by lgkmcnt(0)+sched_barrier+setprio.
// WAR safe: burst targets the non-read buffer; all waves passed the barrier, so
// their previous-tile reads (lgkm-waited before their MFMAs) are complete.
template<int OUTBF>
__global__ __launch_bounds__(512, 2)
void mfma_gemm_256(const u16* __restrict__ A, long ldA, long aHi, long aLo, int modA,
                   const u16* __restrict__ B, long ldB, long bHi, long bLo, int modB,
                   void* __restrict__ Cout, long ldC, long cHi, long cLo, int modC,
                   int M, int N, int K)
{
    __shared__ __align__(16) char smem[131072];   // 2 x (A0 A1 B0 B1) x 16KB

    const int z = blockIdx.z;
    const char* Ab = (const char*)(A + (long)(z / modA) * aHi + (long)(z % modA) * aLo);
    const char* Bb = (const char*)(B + (long)(z / modB) * bHi + (long)(z % modB) * bLo);
    const long ldAb = ldA * 2, ldBb = ldB * 2;

    const int m0 = blockIdx.y * 256, n0 = blockIdx.x * 256;
    const int tid = threadIdx.x;
    const int l = tid & 63;
    const int w = tid >> 6;              // 0..7
    const int wm = w >> 2, wn = w & 3;   // 2M x 4N

    const int srow = l >> 3;
    const int schunk = (l & 7) ^ srow;   // pre-swizzled source chunk (T2)
    const long sgo = (long)schunk * 16;
    const int frow = l & 15, fgrp = l >> 4;
    const int cs0 = (fgrp ^ (l & 7)) * 16;   // swizzled read chunk byte, kk=0

    // halves: 0=A rows[0,128), 1=A rows[128,256), 2=B rows[0,128), 3=B rows[128,256)
    auto stage = [&](int kt, int bsel, int half, int j) {
        const int rr = (w * 2 + j) * 8 + srow;   // 0..127 within half
        const char* gb = (half < 2) ? Ab : Bb;
        const long ld = (half < 2) ? ldAb : ldBb;
        const int gr = ((half < 2) ? m0 + half * 128 : n0 + (half - 2) * 128) + rr;
        gload16(gb + (long)gr * ld + (long)kt * 128 + sgo,
                smem + bsel * 65536 + half * 16384 + (w * 2 + j) * 1024);
    };

    f32x4 acc[2][4][2][2];   // [Qm][mi][Qn][ni]
    const f32x4 zero4 = {0.f, 0.f, 0.f, 0.f};
#pragma unroll
    for (int qm = 0; qm < 2; ++qm)
#pragma unroll
        for (int mi = 0; mi < 4; ++mi)
#pragma unroll
            for (int qn = 0; qn < 2; ++qn)
#pragma unroll
                for (int ni = 0; ni < 2; ++ni) acc[qm][mi][qn][ni] = zero4;

    int aoff[4], boff[2];
#pragma unroll
    for (int mi = 0; mi < 4; ++mi) aoff[mi] = (wm * 64 + mi * 16 + frow) * 128 + cs0;
#pragma unroll
    for (int ni = 0; ni < 2; ++ni) boff[ni] = (wn * 32 + ni * 16 + frow) * 128 + cs0;

    // prologue: burst tile 0 into buffer 0 (8 gloads per wave)
    stage(0, 0, 0, 0); stage(0, 0, 0, 1);
    stage(0, 0, 2, 0); stage(0, 0, 2, 1);
    stage(0, 0, 3, 0); stage(0, 0, 3, 1);
    stage(0, 0, 1, 0); stage(0, 0, 1, 1);

    const int NT = K >> 6;
    for (int kt = 0; kt < NT; ++kt) {
        const char* buf = smem + (kt & 1) * 65536;
        const int sb = (kt & 1) ^ 1;
        const bool pf = (kt + 1) < NT;

        // tile top: only burst(kt) is outstanding -> precise full wait, then the
        // single barrier makes every wave's staged data visible to all.
        asm volatile("s_waitcnt vmcnt(0)" ::: "memory");
        __builtin_amdgcn_s_barrier();

        // issue next tile's burst immediately (slack = 4 phases until its wait)
        if (pf) {
            const int kn = kt + 1;
            stage(kn, sb, 0, 0); stage(kn, sb, 0, 1);
            stage(kn, sb, 2, 0); stage(kn, sb, 2, 1);
            stage(kn, sb, 3, 0); stage(kn, sb, 3, 1);
            stage(kn, sb, 1, 0); stage(kn, sb, 1, 1);
        }

        bf16x8 af[4][2], bq0[2][2], bq1[2][2];

        // ---- p0: Q(0,0) — A-half0 (8 reads) + B-half0 (4 reads) ----
#pragma unroll
        for (int mi = 0; mi < 4; ++mi) {
            af[mi][0] = *(const bf16x8*)(buf + aoff[mi]);
            af[mi][1] = *(const bf16x8*)(buf + (aoff[mi] ^ 64));
        }
#pragma unroll
        for (int ni = 0; ni < 2; ++ni) {
            bq0[ni][0] = *(const bf16x8*)(buf + 32768 + boff[ni]);
            bq0[ni][1] = *(const bf16x8*)(buf + 32768 + (boff[ni] ^ 64));
        }
        asm volatile("s_waitcnt lgkmcnt(0)" ::: "memory");
        __builtin_amdgcn_sched_barrier(0);
        __builtin_amdgcn_s_setprio(1);
#pragma unroll
        for (int kk = 0; kk < 2; ++kk)
#pragma unroll
            for (int mi = 0; mi < 4; ++mi)
#pragma unroll
                for (int ni = 0; ni < 2; ++ni)
                    acc[0][mi][0][ni] = __builtin_amdgcn_mfma_f32_16x16x32_bf16(
                        af[mi][kk], bq0[ni][kk], acc[0][mi][0][ni], 0, 0, 0);
        __builtin_amdgcn_s_setprio(0);

        // ---- p1: Q(0,1) — B-half1 (4 reads) ----
#pragma unroll
        for (int ni = 0; ni < 2; ++ni) {
            bq1[ni][0] = *(const bf16x8*)(buf + 49152 + boff[ni]);
            bq1[ni][1] = *(const bf16x8*)(buf + 49152 + (boff[ni] ^ 64));
        }
        asm volatile("s_waitcnt lgkmcnt(0)" ::: "memory");
        __builtin_amdgcn_sched_barrier(0);
        __builtin_amdgcn_s_setprio(1);
#pragma unroll
        for (int kk = 0; kk < 2; ++kk)
#pragma unroll
            for (int mi = 0; mi < 4; ++mi)
#pragma unroll
                for (int ni = 0; ni < 2; ++ni)
                    acc[0][mi][1][ni] = __builtin_amdgcn_mfma_f32_16x16x32_bf16(
                        af[mi][kk], bq1[ni][kk], acc[0][mi][1][ni], 0, 0, 0);
        __builtin_amdgcn_s_setprio(0);

        // ---- p2: Q(1,1) — A-half1 (8 reads) ----
#pragma unroll
        for (int mi = 0; mi < 4; ++mi) {
            af[mi][0] = *(const bf16x8*)(buf + 16384 + aoff[mi]);
            af[mi][1] = *(const bf16x8*)(buf + 16384 + (aoff[mi] ^ 64));
        }
        asm volatile("s_waitcnt lgkmcnt(0)" ::: "memory");
        __builtin_amdgcn_sched_barrier(0);
        __builtin_amdgcn_s_setprio(1);
#pragma unroll
        for (int kk = 0; kk < 2; ++kk)
#pragma unroll
            for (int mi = 0; mi < 4; ++mi)
#pragma unroll
                for (int ni = 0; ni < 2; ++ni)
                    acc[1][mi][1][ni] = __builtin_amdgcn_mfma_f32_16x16x32_bf16(
                        af[mi][kk], bq1[ni][kk], acc[1][mi][1][ni], 0, 0, 0);
        __builtin_amdgcn_s_setprio(0);

        // ---- p3: Q(1,0) — no reads (af from p2, bq0 from p0) ----
        __builtin_amdgcn_s_setprio(1);
#pragma unroll
        for (int kk = 0; kk < 2; ++kk)
#pragma unroll
            for (int mi = 0; mi < 4; ++mi)
#pragma unroll
                for (int ni = 0; ni < 2; ++ni)
                    acc[1][mi][0][ni] = __builtin_amdgcn_mfma_f32_16x16x32_bf16(
                        af[mi][kk], bq0[ni][kk], acc[1][mi][0][ni], 0, 0, 0);
        __builtin_amdgcn_s_setprio(0);
    }

    // epilogue
    const long cbase = (long)(z / modC) * cHi + (long)(z % modC) * cLo;
#pragma unroll
    for (int qm = 0; qm < 2; ++qm)
#pragma unroll
        for (int mi = 0; mi < 4; ++mi)
#pragma unroll
            for (int qn = 0; qn < 2; ++qn)
#pragma unroll
                for (int ni = 0; ni < 2; ++ni) {
                    const int col = n0 + qn * 128 + wn * 32 + ni * 16 + frow;
                    const int rowb = m0 + qm * 128 + wm * 64 + mi * 16 + fgrp * 4;
#pragma unroll
                    for (int r = 0; r < 4; ++r) {
                        const float v = acc[qm][mi][qn][ni][r];
                        const long idx = cbase + (long)(rowb + r) * ldC + col;
                        if (OUTBF) ((u16*)Cout)[idx] = f2bf(v);
                        else       ((float*)Cout)[idx] = v;
                    }
                }
}

extern "C" void kernel_launch(void* const* d_in, const int* in_sizes, int n_in,
                              void* d_out, int out_size, void* d_ws, size_t ws_size,
                              hipStream_t stream) {
    const float* x    = (const float*)d_in[0];
    const float* mask = (const float*)d_in[1];
    const float* comb = (const float*)d_in[2];
    const float* W1   = (const float*)d_in[3];
    const float* b1   = (const float*)d_in[4];
    const float* W2   = (const float*)d_in[5];
    const float* b2   = (const float*)d_in[6];
    float* out = (float*)d_out;

    char* ws = (char*)d_ws;
    u16* buf0 = (u16*)ws;                    // maskT [16][C][T] -> comb bf16 [2][T][EC]
    u16* xT   = (u16*)(ws + 33554432);       // [2][D][T]        (dead after GEMM1)
    u16* W1b  = (u16*)(ws + 50331648);       // [8][O1][D]       (dead after GEMM2)
    u16* W2b  = (u16*)(ws + 58720256);       // [8][D][O1]       (dead after GEMM3)
    u16* xe   = (u16*)(ws + 67108864);       // [16][C][D] -> yT [2][D][EC]
    u16* h    = (u16*)(ws + 100663296);      // [16][C][O1]
    u16* yT   = xe;
    // GEMM4 split-K partial: fp32 [2][2048][2048] = 33.5 MB in the dead
    // xT..W2b span (33554432 .. 67108864)
    float* part = (float*)(ws + 33554432);

    transpose_conv<<<dim3(DD / 32, TT / 32, BB), 256, 0, stream>>>(
        x, (long)TT * DD, 0L, 1, (long)DD, xT, (long)DD * TT, (long)TT);
    transpose_conv<<<dim3(CCv / 32, TT / 32, BB * EE), 256, 0, stream>>>(
        mask, (long)TT * EE * CCv, (long)CCv, EE, (long)EE * CCv,
        buf0, (long)CCv * TT, (long)TT);
    conv_cast<<<(int)((8L * OO1 * DD) / 1024), 256, 0, stream>>>(W1, W1b, 8L * OO1 * DD);
    conv_cast<<<(int)((8L * DD * OO1) / 1024), 256, 0, stream>>>(W2, W2b, 8L * DD * OO1);

    // GEMM1: xe[z][c][d] = sum_t maskT[z][c][t] * xT[b][d][t] ; M=512,N=2048,K=2048,Z=16
    mfma_gemm_256<1><<<dim3(DD / 256, CCv / 256, 16), 512, 0, stream>>>(
        buf0, 2048, 1048576L, 0L, 1,
        xT,   2048, 4194304L, 0L, 8,
        xe,   2048, 1048576L, 0L, 1,
        CCv, DD, TT);

    conv_cast<<<(int)((2L * TT * EE * CCv) / 1024), 256, 0, stream>>>(
        comb, buf0, 2L * TT * EE * CCv);

    // GEMM2: h = GELU(xe . W1^T + b1) ; M=512,N=256,K=2048,Z=16
    mfma_gemm<1><<<dim3(OO1 / 128, CCv / 128, 16), 256, 0, stream>>>(
        xe,  2048, 1048576L, 0L, 1,
        W1b, 2048, 0L, 524288L, 8,
        h,   256, 131072L, 0L, 1,
        b1, 256L, 8, CCv, OO1, DD);

    // GEMM3T: yT[b][d][e*512+c] = W2 . h^T + b2 ; M=2048,N=512,K=256,Z=16
    mfma_gemm<3><<<dim3(CCv / 128, DD / 128, 16), 256, 0, stream>>>(
        W2b, 256, 0L, 524288L, 8,
        h,   256, 131072L, 0L, 1,
        yT,  4096, 8388608L, 512L, 8,
        b2, 0L, 1, DD, CCv, OO1);

    // GEMM4 split-K=2, one dispatch: z = kh*2 + b (kh = K-half, b = batch).
    // A (comb): base = kh*2048 + b*8388608 ; B (yT): same ; C: kh=0 -> out,
    // kh=1 -> part via runtime element delta. Then out += part.
    const long dPart = (long)((char*)part - (char*)out) / 4;
    mfma_gemm_256<0><<<dim3(DD / 256, TT / 256, 4), 512, 0, stream>>>(
        buf0, 4096, 2048L, 8388608L, 2,
        yT,   4096, 2048L, 8388608L, 2,
        out,  2048, dPart, 4194304L, 2,
        TT, DD, 2048);
    add_inplace<<<8192, 256, 0, stream>>>(out, part);
}